// Round 1
// baseline (4995.563 us; speedup 1.0000x reference)
//
#include <hip/hip_runtime.h>
#include <math.h>

#define B 4
#define N 32768
#define D 131
#define S 1024
#define RAD2 0.1f   // reference compares d2 <= RADIUS (=0.1), i.e. threshold on SQUARED distance

// ---------------------------------------------------------------------------
// Copy x (4x32768x131 f32 = 64MB) straight to out[0 : B*N*D]. float4 grid-stride.
// ---------------------------------------------------------------------------
__global__ void copy_x_kernel(const float* __restrict__ x, float* __restrict__ out) {
    const size_t total4 = (size_t)B * N * D / 4;  // 17170432 / 4 = 4292608
    const float4* __restrict__ src = (const float4*)x;
    float4* __restrict__ dst = (float4*)out;
    for (size_t i = (size_t)blockIdx.x * blockDim.x + threadIdx.x; i < total4;
         i += (size_t)gridDim.x * blockDim.x)
        dst[i] = src[i];
}

// ---------------------------------------------------------------------------
// Pack pts = x[:,:,:3] into SoA in workspace: px[B*N], py[B*N], pz[B*N].
// ---------------------------------------------------------------------------
__global__ void pack_kernel(const float* __restrict__ x, float* __restrict__ ws) {
    int i = blockIdx.x * blockDim.x + threadIdx.x;
    if (i < B * N) {
        const float* __restrict__ s = x + (size_t)i * D;
        ws[i]             = s[0];
        ws[B * N + i]     = s[1];
        ws[2 * B * N + i] = s[2];
    }
}

// ---------------------------------------------------------------------------
// FPS: one block per batch. 512 threads x 64 pts/thread.
// x,y coords + closest in VGPRs; z coords in LDS (128 KiB).
// Bit-exact float32: no FMA contraction, fminf, argmax first-index tie-break.
// ---------------------------------------------------------------------------
__launch_bounds__(512, 2)
__global__ void fps_kernel(const float* __restrict__ ws,
                           float* __restrict__ out_idx,
                           int* __restrict__ idx_int) {
    __shared__ float s_pz[N];      // 128 KiB
    __shared__ float s_rv[8];
    __shared__ int   s_ri[8];
    __shared__ int   s_sel;

    const int b = blockIdx.x;
    const int t = threadIdx.x;
    const float* __restrict__ px = ws + (size_t)b * N;
    const float* __restrict__ py = ws + (size_t)(B + b) * N;
    const float* __restrict__ pz = ws + (size_t)(2 * B + b) * N;

    // Thread t owns points p = 2*t + 1024*i + {0,1}, i = 0..31  (ascending p).
    float lx[64], ly[64], lcl[64];
    #pragma unroll
    for (int i = 0; i < 32; ++i) {
        int p = 2 * t + 1024 * i;
        float2 vx = *(const float2*)&px[p];
        float2 vy = *(const float2*)&py[p];
        float2 vz = *(const float2*)&pz[p];
        lx[2 * i] = vx.x; lx[2 * i + 1] = vx.y;
        ly[2 * i] = vy.x; ly[2 * i + 1] = vy.y;
        *(float2*)&s_pz[p] = vz;
        lcl[2 * i] = INFINITY; lcl[2 * i + 1] = INFINITY;
    }
    __syncthreads();

    int sel = 0;
    for (int s = 0; s < S; ++s) {
        // centroid coords: wave-uniform broadcast load (L2) + LDS for z
        float cx = px[sel];
        float cy = py[sel];
        float cz = s_pz[sel];

        float best = -INFINITY;
        int   bidx = 0;
        #pragma unroll
        for (int i = 0; i < 32; ++i) {
            int p = 2 * t + 1024 * i;
            float2 zz = *(const float2*)&s_pz[p];
            {
                float dx = __fsub_rn(cx, lx[2 * i]);
                float dy = __fsub_rn(cy, ly[2 * i]);
                float dz = __fsub_rn(cz, zz.x);
                float d2 = __fadd_rn(__fadd_rn(__fmul_rn(dx, dx), __fmul_rn(dy, dy)),
                                     __fmul_rn(dz, dz));
                float c = fminf(lcl[2 * i], d2);
                lcl[2 * i] = c;
                if (c > best) { best = c; bidx = p; }       // strict > keeps smallest p
            }
            {
                float dx = __fsub_rn(cx, lx[2 * i + 1]);
                float dy = __fsub_rn(cy, ly[2 * i + 1]);
                float dz = __fsub_rn(cz, zz.y);
                float d2 = __fadd_rn(__fadd_rn(__fmul_rn(dx, dx), __fmul_rn(dy, dy)),
                                     __fmul_rn(dz, dz));
                float c = fminf(lcl[2 * i + 1], d2);
                lcl[2 * i + 1] = c;
                if (c > best) { best = c; bidx = p + 1; }
            }
        }

        // wave (64-lane) butterfly argmax with first-index tie-break
        #pragma unroll
        for (int off = 1; off < 64; off <<= 1) {
            float ov = __shfl_xor(best, off, 64);
            int   op = __shfl_xor(bidx, off, 64);
            if (ov > best || (ov == best && op < bidx)) { best = ov; bidx = op; }
        }
        if ((t & 63) == 0) { s_rv[t >> 6] = best; s_ri[t >> 6] = bidx; }
        __syncthreads();
        if (t == 0) {
            float bv = s_rv[0]; int bi = s_ri[0];
            #pragma unroll
            for (int w = 1; w < 8; ++w) {
                float v = s_rv[w]; int p2 = s_ri[w];
                if (v > bv || (v == bv && p2 < bi)) { bv = v; bi = p2; }
            }
            s_sel = bi;
            out_idx[b * S + s] = (float)bi;   // harness reads flat buffer as f32
            idx_int[b * S + s] = bi;
        }
        __syncthreads();
        sel = s_sel;
    }
}

// ---------------------------------------------------------------------------
// Ball query counts: one block (256 thr) per (batch, centroid). Reads packed SoA.
// ---------------------------------------------------------------------------
__launch_bounds__(256)
__global__ void ballq_kernel(const float* __restrict__ ws,
                             const int* __restrict__ idx_int,
                             float* __restrict__ out_counts) {
    __shared__ int s_part[4];
    const int b = blockIdx.x >> 10;
    const int j = blockIdx.x & 1023;
    const int t = threadIdx.x;
    const float* __restrict__ px = ws + (size_t)b * N;
    const float* __restrict__ py = ws + (size_t)(B + b) * N;
    const float* __restrict__ pz = ws + (size_t)(2 * B + b) * N;

    const int ci = idx_int[b * S + j];
    const float cx = px[ci], cy = py[ci], cz = pz[ci];

    int cnt = 0;
    #pragma unroll 4
    for (int p = t; p < N; p += 256) {
        float dx = __fsub_rn(cx, px[p]);
        float dy = __fsub_rn(cy, py[p]);
        float dz = __fsub_rn(cz, pz[p]);
        float d2 = __fadd_rn(__fadd_rn(__fmul_rn(dx, dx), __fmul_rn(dy, dy)),
                             __fmul_rn(dz, dz));
        cnt += (d2 <= RAD2) ? 1 : 0;
    }
    #pragma unroll
    for (int off = 1; off < 64; off <<= 1)
        cnt += __shfl_xor(cnt, off, 64);
    if ((t & 63) == 0) s_part[t >> 6] = cnt;
    __syncthreads();
    if (t == 0)
        out_counts[b * S + j] = (float)(s_part[0] + s_part[1] + s_part[2] + s_part[3]);
}

// ---------------------------------------------------------------------------
extern "C" void kernel_launch(void* const* d_in, const int* in_sizes, int n_in,
                              void* d_out, int out_size, void* d_ws, size_t ws_size,
                              hipStream_t stream) {
    const float* x = (const float*)d_in[0];
    float* out = (float*)d_out;
    float* ws = (float*)d_ws;                 // px|py|pz SoA then idx ints
    int* idx_int = (int*)(ws + (size_t)3 * B * N);

    float* out_x      = out;                              // B*N*D floats
    float* out_idx    = out + (size_t)B * N * D;          // B*S floats (idx as f32)
    float* out_counts = out_idx + (size_t)B * S;          // B*S floats (counts as f32)

    hipLaunchKernelGGL(pack_kernel, dim3((B * N + 255) / 256), dim3(256), 0, stream, x, ws);
    hipLaunchKernelGGL(copy_x_kernel, dim3(2048), dim3(256), 0, stream, x, out_x);
    hipLaunchKernelGGL(fps_kernel, dim3(B), dim3(512), 0, stream, ws, out_idx, idx_int);
    hipLaunchKernelGGL(ballq_kernel, dim3(B * S), dim3(256), 0, stream, ws, idx_int, out_counts);
}

// Round 2
// 4828.997 us; speedup vs baseline: 1.0345x; 1.0345x over previous
//
#include <hip/hip_runtime.h>
#include <math.h>

#define B 4
#define N 32768
#define D 131
#define S 1024
#define RAD2 0.1f   // reference compares d2 <= RADIUS (=0.1) on SQUARED distance

// ---------------------------------------------------------------------------
// Copy x (4x32768x131 f32 = 64MB) straight to out. float4 grid-stride.
// ---------------------------------------------------------------------------
__global__ void copy_x_kernel(const float* __restrict__ x, float* __restrict__ out) {
    const size_t total4 = (size_t)B * N * D / 4;
    const float4* __restrict__ src = (const float4*)x;
    float4* __restrict__ dst = (float4*)out;
    for (size_t i = (size_t)blockIdx.x * blockDim.x + threadIdx.x; i < total4;
         i += (size_t)gridDim.x * blockDim.x)
        dst[i] = src[i];
}

// ---------------------------------------------------------------------------
// Pack pts = x[:,:,:3] into SoA (px|py|pz) AND packed float4 {x,y,z,0} for the
// per-step centroid gather (one dwordx4 L2 round-trip).
// ---------------------------------------------------------------------------
__global__ void pack_kernel(const float* __restrict__ x, float* __restrict__ ws) {
    int i = blockIdx.x * blockDim.x + threadIdx.x;
    if (i < B * N) {
        const float* __restrict__ s = x + (size_t)i * D;
        float a = s[0], bb = s[1], c = s[2];
        ws[i]             = a;
        ws[B * N + i]     = bb;
        ws[2 * B * N + i] = c;
        float4* w4 = (float4*)(ws + (size_t)3 * B * N);
        w4[i] = make_float4(a, bb, c, 0.0f);
    }
}

// ---------------------------------------------------------------------------
// FPS: one block per batch. 512 threads x 64 pts/thread.
// x,y,closest in VGPRs (192 regs -> need 256-VGPR budget: waves_per_eu(2,2)),
// z in LDS (128 KiB). One barrier per step, double-buffered reduction slots.
// Packed (value_bits<<32 | ~idx) u64 max == argmax with first-index tie-break.
// ---------------------------------------------------------------------------
__launch_bounds__(512)
__attribute__((amdgpu_waves_per_eu(2, 2)))
__global__ void fps_kernel(const float* __restrict__ ws,
                           float* __restrict__ out_idx,
                           int* __restrict__ idx_int) {
    __shared__ float s_pz[N];                    // 128 KiB
    __shared__ unsigned long long s_slot[2][8];  // double-buffered wave results

    const int b = blockIdx.x;
    const int t = threadIdx.x;
    const float* __restrict__ px = ws + (size_t)b * N;
    const float* __restrict__ py = ws + (size_t)(B + b) * N;
    const float* __restrict__ pz = ws + (size_t)(2 * B + b) * N;
    const float4* __restrict__ p4 = (const float4*)(ws + (size_t)3 * B * N) + (size_t)b * N;

    // Thread t owns points p = 2*t + 1024*i + {0,1}, i = 0..31 (ascending p).
    float lx[64], ly[64], lcl[64];
    #pragma unroll
    for (int i = 0; i < 32; ++i) {
        int p = 2 * t + 1024 * i;
        float2 vx = *(const float2*)&px[p];
        float2 vy = *(const float2*)&py[p];
        float2 vz = *(const float2*)&pz[p];
        lx[2 * i] = vx.x; lx[2 * i + 1] = vx.y;
        ly[2 * i] = vy.x; ly[2 * i + 1] = vy.y;
        *(float2*)&s_pz[p] = vz;
        lcl[2 * i] = INFINITY; lcl[2 * i + 1] = INFINITY;
    }
    __syncthreads();

    float4 c4 = p4[0];   // centroid 0 coords (reference starts at sel=0)

    for (int s = 0; s < S; ++s) {
        const float cx = c4.x, cy = c4.y, cz = c4.z;

        float best = -INFINITY;
        int   bidx = 0;
        #pragma unroll
        for (int i = 0; i < 32; ++i) {
            const int p = 2 * t + 1024 * i;
            float2 zz = *(const float2*)&s_pz[p];
            {
                float dx = __fsub_rn(cx, lx[2 * i]);
                float dy = __fsub_rn(cy, ly[2 * i]);
                float dz = __fsub_rn(cz, zz.x);
                float d2 = __fadd_rn(__fadd_rn(__fmul_rn(dx, dx), __fmul_rn(dy, dy)),
                                     __fmul_rn(dz, dz));
                float c = fminf(lcl[2 * i], d2);
                lcl[2 * i] = c;
                if (c > best) { best = c; bidx = p; }     // strict >: keeps smallest p
            }
            {
                float dx = __fsub_rn(cx, lx[2 * i + 1]);
                float dy = __fsub_rn(cy, ly[2 * i + 1]);
                float dz = __fsub_rn(cz, zz.y);
                float d2 = __fadd_rn(__fadd_rn(__fmul_rn(dx, dx), __fmul_rn(dy, dy)),
                                     __fmul_rn(dz, dz));
                float c = fminf(lcl[2 * i + 1], d2);
                lcl[2 * i + 1] = c;
                if (c > best) { best = c; bidx = p + 1; }
            }
        }

        // Packed key: larger == (bigger value, then smaller index).
        // best >= 0 always (squared distances after first min), so float bits
        // compare like the float itself.
        unsigned hi = __float_as_uint(best);
        unsigned lo = ~(unsigned)bidx;

        #define FPS_COMBINE(OHI, OLO) \
            { unsigned _oh = (OHI), _ol = (OLO); \
              if (_oh > hi || (_oh == hi && _ol > lo)) { hi = _oh; lo = _ol; } }

        // lanes ^1, ^2 : quad_perm ; ^4 : row_half_mirror ; ^8 : row_mirror
        { unsigned a = (unsigned)__builtin_amdgcn_update_dpp(0, (int)hi, 0xB1, 0xf, 0xf, true);
          unsigned c2 = (unsigned)__builtin_amdgcn_update_dpp(0, (int)lo, 0xB1, 0xf, 0xf, true);
          FPS_COMBINE(a, c2); }
        { unsigned a = (unsigned)__builtin_amdgcn_update_dpp(0, (int)hi, 0x4E, 0xf, 0xf, true);
          unsigned c2 = (unsigned)__builtin_amdgcn_update_dpp(0, (int)lo, 0x4E, 0xf, 0xf, true);
          FPS_COMBINE(a, c2); }
        { unsigned a = (unsigned)__builtin_amdgcn_update_dpp(0, (int)hi, 0x141, 0xf, 0xf, true);
          unsigned c2 = (unsigned)__builtin_amdgcn_update_dpp(0, (int)lo, 0x141, 0xf, 0xf, true);
          FPS_COMBINE(a, c2); }
        { unsigned a = (unsigned)__builtin_amdgcn_update_dpp(0, (int)hi, 0x140, 0xf, 0xf, true);
          unsigned c2 = (unsigned)__builtin_amdgcn_update_dpp(0, (int)lo, 0x140, 0xf, 0xf, true);
          FPS_COMBINE(a, c2); }
        // lane ^16 : ds_swizzle bitmode xor16 (offset 0x401F)
        { unsigned a = (unsigned)__builtin_amdgcn_ds_swizzle((int)hi, 0x401F);
          unsigned c2 = (unsigned)__builtin_amdgcn_ds_swizzle((int)lo, 0x401F);
          FPS_COMBINE(a, c2); }
        // lane ^32 : cross-half
        { unsigned a = (unsigned)__shfl_xor((int)hi, 32, 64);
          unsigned c2 = (unsigned)__shfl_xor((int)lo, 32, 64);
          FPS_COMBINE(a, c2); }
        #undef FPS_COMBINE

        const int buf = s & 1;
        if ((t & 63) == 0)
            s_slot[buf][t >> 6] = ((unsigned long long)hi << 32) | lo;
        __syncthreads();   // the ONLY barrier per step (slots double-buffered)

        // All threads redundantly reduce the 8 wave results (broadcast reads).
        unsigned long long g = s_slot[buf][0];
        #pragma unroll
        for (int w = 1; w < 8; ++w) {
            unsigned long long v = s_slot[buf][w];
            if (v > g) g = v;
        }
        const int sel = (int)(~(unsigned)g);

        c4 = p4[sel];      // wave-uniform gather of next centroid (1 dwordx4)

        if (t == 0) {
            out_idx[b * S + s] = (float)sel;
            idx_int[b * S + s] = sel;
        }
    }
}

// ---------------------------------------------------------------------------
// Ball query counts: one block (256 thr) per (batch, centroid).
// ---------------------------------------------------------------------------
__launch_bounds__(256)
__global__ void ballq_kernel(const float* __restrict__ ws,
                             const int* __restrict__ idx_int,
                             float* __restrict__ out_counts) {
    __shared__ int s_part[4];
    const int b = blockIdx.x >> 10;
    const int j = blockIdx.x & 1023;
    const int t = threadIdx.x;
    const float* __restrict__ px = ws + (size_t)b * N;
    const float* __restrict__ py = ws + (size_t)(B + b) * N;
    const float* __restrict__ pz = ws + (size_t)(2 * B + b) * N;

    const int ci = idx_int[b * S + j];
    const float cx = px[ci], cy = py[ci], cz = pz[ci];

    int cnt = 0;
    #pragma unroll 4
    for (int p = t; p < N; p += 256) {
        float dx = __fsub_rn(cx, px[p]);
        float dy = __fsub_rn(cy, py[p]);
        float dz = __fsub_rn(cz, pz[p]);
        float d2 = __fadd_rn(__fadd_rn(__fmul_rn(dx, dx), __fmul_rn(dy, dy)),
                             __fmul_rn(dz, dz));
        cnt += (d2 <= RAD2) ? 1 : 0;
    }
    #pragma unroll
    for (int off = 1; off < 64; off <<= 1)
        cnt += __shfl_xor(cnt, off, 64);
    if ((t & 63) == 0) s_part[t >> 6] = cnt;
    __syncthreads();
    if (t == 0)
        out_counts[b * S + j] = (float)(s_part[0] + s_part[1] + s_part[2] + s_part[3]);
}

// ---------------------------------------------------------------------------
extern "C" void kernel_launch(void* const* d_in, const int* in_sizes, int n_in,
                              void* d_out, int out_size, void* d_ws, size_t ws_size,
                              hipStream_t stream) {
    const float* x = (const float*)d_in[0];
    float* out = (float*)d_out;
    float* ws = (float*)d_ws;                       // px|py|pz SoA, float4 pack, idx ints
    int* idx_int = (int*)(ws + (size_t)7 * B * N);  // after SoA (3BN) + float4 (4BN)

    float* out_x      = out;                         // B*N*D floats
    float* out_idx    = out + (size_t)B * N * D;     // B*S floats (idx as f32)
    float* out_counts = out_idx + (size_t)B * S;     // B*S floats (counts as f32)

    hipLaunchKernelGGL(pack_kernel, dim3((B * N + 255) / 256), dim3(256), 0, stream, x, ws);
    hipLaunchKernelGGL(copy_x_kernel, dim3(2048), dim3(256), 0, stream, x, out_x);
    hipLaunchKernelGGL(fps_kernel, dim3(B), dim3(512), 0, stream, ws, out_idx, idx_int);
    hipLaunchKernelGGL(ballq_kernel, dim3(B * S), dim3(256), 0, stream, ws, idx_int, out_counts);
}

// Round 3
// 4511.885 us; speedup vs baseline: 1.1072x; 1.0703x over previous
//
#include <hip/hip_runtime.h>
#include <math.h>

#define B 4
#define N 32768
#define D 131
#define S 1024
#define RAD2 0.1f   // reference compares d2 <= RADIUS (=0.1) on SQUARED distance

// ---------------------------------------------------------------------------
// Copy x (4x32768x131 f32 = 64MB) straight to out. float4 grid-stride.
// ---------------------------------------------------------------------------
__global__ void copy_x_kernel(const float* __restrict__ x, float* __restrict__ out) {
    const size_t total4 = (size_t)B * N * D / 4;
    const float4* __restrict__ src = (const float4*)x;
    float4* __restrict__ dst = (float4*)out;
    for (size_t i = (size_t)blockIdx.x * blockDim.x + threadIdx.x; i < total4;
         i += (size_t)gridDim.x * blockDim.x)
        dst[i] = src[i];
}

// ---------------------------------------------------------------------------
// Pack pts = x[:,:,:3] into SoA (px|py|pz) AND packed float4 {x,y,z,0} for the
// per-step centroid gather (one dwordx4 L2 round-trip).
// ---------------------------------------------------------------------------
__global__ void pack_kernel(const float* __restrict__ x, float* __restrict__ ws) {
    int i = blockIdx.x * blockDim.x + threadIdx.x;
    if (i < B * N) {
        const float* __restrict__ s = x + (size_t)i * D;
        float a = s[0], bb = s[1], c = s[2];
        ws[i]             = a;
        ws[B * N + i]     = bb;
        ws[2 * B * N + i] = c;
        float4* w4 = (float4*)(ws + (size_t)3 * B * N);
        w4[i] = make_float4(a, bb, c, 0.0f);
    }
}

// ---------------------------------------------------------------------------
// FPS: one block per batch. 1024 threads x 32 pts/thread.
// Per-thread state lx[32]+ly[32]+lcl[32] = 96 VGPRs -> fits the 128-VGPR
// budget a 16-wave workgroup forces (4 waves/SIMD co-resident). No spills.
// z in LDS (128 KiB). One barrier per step, double-buffered reduction slots.
// Packed (value_bits<<32 | ~idx) u64 max == argmax with first-index tie-break.
// ---------------------------------------------------------------------------
__launch_bounds__(1024, 4)
__global__ void fps_kernel(const float* __restrict__ ws,
                           float* __restrict__ out_idx,
                           int* __restrict__ idx_int) {
    __shared__ float s_pz[N];                     // 128 KiB
    __shared__ unsigned long long s_slot[2][16];  // double-buffered wave results

    const int b = blockIdx.x;
    const int t = threadIdx.x;
    const float* __restrict__ px = ws + (size_t)b * N;
    const float* __restrict__ py = ws + (size_t)(B + b) * N;
    const float* __restrict__ pz = ws + (size_t)(2 * B + b) * N;
    const float4* __restrict__ p4 = (const float4*)(ws + (size_t)3 * B * N) + (size_t)b * N;

    // Thread t owns points p = 2*t + 2048*i + {0,1}, i = 0..15 (ascending p).
    float lx[32], ly[32], lcl[32];
    #pragma unroll
    for (int i = 0; i < 16; ++i) {
        int p = 2 * t + 2048 * i;
        float2 vx = *(const float2*)&px[p];
        float2 vy = *(const float2*)&py[p];
        float2 vz = *(const float2*)&pz[p];
        lx[2 * i] = vx.x; lx[2 * i + 1] = vx.y;
        ly[2 * i] = vy.x; ly[2 * i + 1] = vy.y;
        *(float2*)&s_pz[p] = vz;
        lcl[2 * i] = INFINITY; lcl[2 * i + 1] = INFINITY;
    }
    __syncthreads();

    float4 c4 = p4[0];   // centroid 0 coords (reference starts at sel=0)

    for (int s = 0; s < S; ++s) {
        const float cx = c4.x, cy = c4.y, cz = c4.z;

        float best = -INFINITY;
        int   bidx = 0;
        #pragma unroll
        for (int i = 0; i < 16; ++i) {
            const int p = 2 * t + 2048 * i;
            float2 zz = *(const float2*)&s_pz[p];
            {
                float dx = __fsub_rn(cx, lx[2 * i]);
                float dy = __fsub_rn(cy, ly[2 * i]);
                float dz = __fsub_rn(cz, zz.x);
                float d2 = __fadd_rn(__fadd_rn(__fmul_rn(dx, dx), __fmul_rn(dy, dy)),
                                     __fmul_rn(dz, dz));
                float c = fminf(lcl[2 * i], d2);
                lcl[2 * i] = c;
                if (c > best) { best = c; bidx = p; }     // strict >: keeps smallest p
            }
            {
                float dx = __fsub_rn(cx, lx[2 * i + 1]);
                float dy = __fsub_rn(cy, ly[2 * i + 1]);
                float dz = __fsub_rn(cz, zz.y);
                float d2 = __fadd_rn(__fadd_rn(__fmul_rn(dx, dx), __fmul_rn(dy, dy)),
                                     __fmul_rn(dz, dz));
                float c = fminf(lcl[2 * i + 1], d2);
                lcl[2 * i + 1] = c;
                if (c > best) { best = c; bidx = p + 1; }
            }
        }

        // Packed key: larger == (bigger value, then smaller index).
        // best >= 0 always after step 0, and at step 0 all-inf compares fine.
        unsigned hi = __float_as_uint(best);
        unsigned lo = ~(unsigned)bidx;

        #define FPS_COMBINE(OHI, OLO) \
            { unsigned _oh = (OHI), _ol = (OLO); \
              if (_oh > hi || (_oh == hi && _ol > lo)) { hi = _oh; lo = _ol; } }

        // lanes ^1, ^2 : quad_perm ; ^4 : row_half_mirror ; ^8 : row_mirror
        { unsigned a = (unsigned)__builtin_amdgcn_update_dpp(0, (int)hi, 0xB1, 0xf, 0xf, true);
          unsigned c2 = (unsigned)__builtin_amdgcn_update_dpp(0, (int)lo, 0xB1, 0xf, 0xf, true);
          FPS_COMBINE(a, c2); }
        { unsigned a = (unsigned)__builtin_amdgcn_update_dpp(0, (int)hi, 0x4E, 0xf, 0xf, true);
          unsigned c2 = (unsigned)__builtin_amdgcn_update_dpp(0, (int)lo, 0x4E, 0xf, 0xf, true);
          FPS_COMBINE(a, c2); }
        { unsigned a = (unsigned)__builtin_amdgcn_update_dpp(0, (int)hi, 0x141, 0xf, 0xf, true);
          unsigned c2 = (unsigned)__builtin_amdgcn_update_dpp(0, (int)lo, 0x141, 0xf, 0xf, true);
          FPS_COMBINE(a, c2); }
        { unsigned a = (unsigned)__builtin_amdgcn_update_dpp(0, (int)hi, 0x140, 0xf, 0xf, true);
          unsigned c2 = (unsigned)__builtin_amdgcn_update_dpp(0, (int)lo, 0x140, 0xf, 0xf, true);
          FPS_COMBINE(a, c2); }
        // lane ^16 : ds_swizzle bitmode xor16 (offset 0x401F)
        { unsigned a = (unsigned)__builtin_amdgcn_ds_swizzle((int)hi, 0x401F);
          unsigned c2 = (unsigned)__builtin_amdgcn_ds_swizzle((int)lo, 0x401F);
          FPS_COMBINE(a, c2); }
        // lane ^32 : cross-half
        { unsigned a = (unsigned)__shfl_xor((int)hi, 32, 64);
          unsigned c2 = (unsigned)__shfl_xor((int)lo, 32, 64);
          FPS_COMBINE(a, c2); }
        #undef FPS_COMBINE

        const int buf = s & 1;
        if ((t & 63) == 0)
            s_slot[buf][t >> 6] = ((unsigned long long)hi << 32) | lo;
        __syncthreads();   // the ONLY barrier per step (slots double-buffered)

        // All threads redundantly reduce the 16 wave results (broadcast reads).
        unsigned long long g = s_slot[buf][0];
        #pragma unroll
        for (int w = 1; w < 16; ++w) {
            unsigned long long v = s_slot[buf][w];
            if (v > g) g = v;
        }
        const int sel = (int)(~(unsigned)g);

        c4 = p4[sel];      // wave-uniform gather of next centroid (1 dwordx4)

        if (t == 0) {
            out_idx[b * S + s] = (float)sel;
            idx_int[b * S + s] = sel;
        }
    }
}

// ---------------------------------------------------------------------------
// Ball query counts: one block (256 thr) per (batch, centroid).
// ---------------------------------------------------------------------------
__launch_bounds__(256)
__global__ void ballq_kernel(const float* __restrict__ ws,
                             const int* __restrict__ idx_int,
                             float* __restrict__ out_counts) {
    __shared__ int s_part[4];
    const int b = blockIdx.x >> 10;
    const int j = blockIdx.x & 1023;
    const int t = threadIdx.x;
    const float* __restrict__ px = ws + (size_t)b * N;
    const float* __restrict__ py = ws + (size_t)(B + b) * N;
    const float* __restrict__ pz = ws + (size_t)(2 * B + b) * N;

    const int ci = idx_int[b * S + j];
    const float cx = px[ci], cy = py[ci], cz = pz[ci];

    int cnt = 0;
    #pragma unroll 4
    for (int p = t; p < N; p += 256) {
        float dx = __fsub_rn(cx, px[p]);
        float dy = __fsub_rn(cy, py[p]);
        float dz = __fsub_rn(cz, pz[p]);
        float d2 = __fadd_rn(__fadd_rn(__fmul_rn(dx, dx), __fmul_rn(dy, dy)),
                             __fmul_rn(dz, dz));
        cnt += (d2 <= RAD2) ? 1 : 0;
    }
    #pragma unroll
    for (int off = 1; off < 64; off <<= 1)
        cnt += __shfl_xor(cnt, off, 64);
    if ((t & 63) == 0) s_part[t >> 6] = cnt;
    __syncthreads();
    if (t == 0)
        out_counts[b * S + j] = (float)(s_part[0] + s_part[1] + s_part[2] + s_part[3]);
}

// ---------------------------------------------------------------------------
extern "C" void kernel_launch(void* const* d_in, const int* in_sizes, int n_in,
                              void* d_out, int out_size, void* d_ws, size_t ws_size,
                              hipStream_t stream) {
    const float* x = (const float*)d_in[0];
    float* out = (float*)d_out;
    float* ws = (float*)d_ws;                       // px|py|pz SoA, float4 pack, idx ints
    int* idx_int = (int*)(ws + (size_t)7 * B * N);  // after SoA (3BN) + float4 (4BN)

    float* out_x      = out;                         // B*N*D floats
    float* out_idx    = out + (size_t)B * N * D;     // B*S floats (idx as f32)
    float* out_counts = out_idx + (size_t)B * S;     // B*S floats (counts as f32)

    hipLaunchKernelGGL(pack_kernel, dim3((B * N + 255) / 256), dim3(256), 0, stream, x, ws);
    hipLaunchKernelGGL(copy_x_kernel, dim3(2048), dim3(256), 0, stream, x, out_x);
    hipLaunchKernelGGL(fps_kernel, dim3(B), dim3(1024), 0, stream, ws, out_idx, idx_int);
    hipLaunchKernelGGL(ballq_kernel, dim3(B * S), dim3(256), 0, stream, ws, idx_int, out_counts);
}

// Round 4
// 4510.462 us; speedup vs baseline: 1.1076x; 1.0003x over previous
//
#include <hip/hip_runtime.h>
#include <math.h>

#define B 4
#define N 32768
#define D 131
#define S 1024
#define RAD2 0.1f   // reference compares d2 <= RADIUS (=0.1) on SQUARED distance

// ---------------------------------------------------------------------------
// Copy x (4x32768x131 f32 = 64MB) straight to out. float4 grid-stride.
// ---------------------------------------------------------------------------
__global__ void copy_x_kernel(const float* __restrict__ x, float* __restrict__ out) {
    const size_t total4 = (size_t)B * N * D / 4;
    const float4* __restrict__ src = (const float4*)x;
    float4* __restrict__ dst = (float4*)out;
    for (size_t i = (size_t)blockIdx.x * blockDim.x + threadIdx.x; i < total4;
         i += (size_t)gridDim.x * blockDim.x)
        dst[i] = src[i];
}

// ---------------------------------------------------------------------------
// Pack pts = x[:,:,:3] into SoA (px|py|pz) AND packed float4 {x,y,z,0} for the
// per-step centroid gather (one dwordx4 L2 round-trip).
// ---------------------------------------------------------------------------
__global__ void pack_kernel(const float* __restrict__ x, float* __restrict__ ws) {
    int i = blockIdx.x * blockDim.x + threadIdx.x;
    if (i < B * N) {
        const float* __restrict__ s = x + (size_t)i * D;
        float a = s[0], bb = s[1], c = s[2];
        ws[i]             = a;
        ws[B * N + i]     = bb;
        ws[2 * B * N + i] = c;
        float4* w4 = (float4*)(ws + (size_t)3 * B * N);
        w4[i] = make_float4(a, bb, c, 0.0f);
    }
}

// ---------------------------------------------------------------------------
// FPS: one block per batch. 1024 threads x 32 pts/thread.
// Per-thread state lx[32]+ly[32]+lcl[32] = 96 VGPRs; a 1024-thread block is
// exactly 4 waves/EU, so amdgpu_waves_per_eu(4,4) => 128-VGPR budget, which
// fits the state WITHOUT spills. (launch_bounds 2nd arg proved to be
// CUDA-style min-blocks/CU on hipcc: (1024,4) forced a 64-VGPR budget.)
// z in LDS (128 KiB). One barrier per step, double-buffered reduction slots.
// Packed (value_bits<<32 | ~idx) u64 max == argmax with first-index tie-break.
// ---------------------------------------------------------------------------
__launch_bounds__(1024)
__attribute__((amdgpu_waves_per_eu(4, 4)))
__global__ void fps_kernel(const float* __restrict__ ws,
                           float* __restrict__ out_idx,
                           int* __restrict__ idx_int) {
    __shared__ float s_pz[N];                     // 128 KiB
    __shared__ unsigned long long s_slot[2][16];  // double-buffered wave results

    const int b = blockIdx.x;
    const int t = threadIdx.x;
    const float* __restrict__ px = ws + (size_t)b * N;
    const float* __restrict__ py = ws + (size_t)(B + b) * N;
    const float* __restrict__ pz = ws + (size_t)(2 * B + b) * N;
    const float4* __restrict__ p4 = (const float4*)(ws + (size_t)3 * B * N) + (size_t)b * N;

    // Thread t owns points p = 2*t + 2048*i + {0,1}, i = 0..15 (ascending p).
    float lx[32], ly[32], lcl[32];
    #pragma unroll
    for (int i = 0; i < 16; ++i) {
        int p = 2 * t + 2048 * i;
        float2 vx = *(const float2*)&px[p];
        float2 vy = *(const float2*)&py[p];
        float2 vz = *(const float2*)&pz[p];
        lx[2 * i] = vx.x; lx[2 * i + 1] = vx.y;
        ly[2 * i] = vy.x; ly[2 * i + 1] = vy.y;
        *(float2*)&s_pz[p] = vz;
        lcl[2 * i] = INFINITY; lcl[2 * i + 1] = INFINITY;
    }
    __syncthreads();

    float4 c4 = p4[0];   // centroid 0 coords (reference starts at sel=0)

    for (int s = 0; s < S; ++s) {
        const float cx = c4.x, cy = c4.y, cz = c4.z;

        float best = -INFINITY;
        int   bidx = 0;
        #pragma unroll
        for (int i = 0; i < 16; ++i) {
            const int p = 2 * t + 2048 * i;
            float2 zz = *(const float2*)&s_pz[p];
            {
                float dx = __fsub_rn(cx, lx[2 * i]);
                float dy = __fsub_rn(cy, ly[2 * i]);
                float dz = __fsub_rn(cz, zz.x);
                float d2 = __fadd_rn(__fadd_rn(__fmul_rn(dx, dx), __fmul_rn(dy, dy)),
                                     __fmul_rn(dz, dz));
                float c = fminf(lcl[2 * i], d2);
                lcl[2 * i] = c;
                if (c > best) { best = c; bidx = p; }     // strict >: keeps smallest p
            }
            {
                float dx = __fsub_rn(cx, lx[2 * i + 1]);
                float dy = __fsub_rn(cy, ly[2 * i + 1]);
                float dz = __fsub_rn(cz, zz.y);
                float d2 = __fadd_rn(__fadd_rn(__fmul_rn(dx, dx), __fmul_rn(dy, dy)),
                                     __fmul_rn(dz, dz));
                float c = fminf(lcl[2 * i + 1], d2);
                lcl[2 * i + 1] = c;
                if (c > best) { best = c; bidx = p + 1; }
            }
        }

        // Packed key: larger == (bigger value, then smaller index).
        unsigned hi = __float_as_uint(best);
        unsigned lo = ~(unsigned)bidx;

        #define FPS_COMBINE(OHI, OLO) \
            { unsigned _oh = (OHI), _ol = (OLO); \
              if (_oh > hi || (_oh == hi && _ol > lo)) { hi = _oh; lo = _ol; } }

        // lanes ^1, ^2 : quad_perm ; ^4 : row_half_mirror ; ^8 : row_mirror
        { unsigned a = (unsigned)__builtin_amdgcn_update_dpp(0, (int)hi, 0xB1, 0xf, 0xf, true);
          unsigned c2 = (unsigned)__builtin_amdgcn_update_dpp(0, (int)lo, 0xB1, 0xf, 0xf, true);
          FPS_COMBINE(a, c2); }
        { unsigned a = (unsigned)__builtin_amdgcn_update_dpp(0, (int)hi, 0x4E, 0xf, 0xf, true);
          unsigned c2 = (unsigned)__builtin_amdgcn_update_dpp(0, (int)lo, 0x4E, 0xf, 0xf, true);
          FPS_COMBINE(a, c2); }
        { unsigned a = (unsigned)__builtin_amdgcn_update_dpp(0, (int)hi, 0x141, 0xf, 0xf, true);
          unsigned c2 = (unsigned)__builtin_amdgcn_update_dpp(0, (int)lo, 0x141, 0xf, 0xf, true);
          FPS_COMBINE(a, c2); }
        { unsigned a = (unsigned)__builtin_amdgcn_update_dpp(0, (int)hi, 0x140, 0xf, 0xf, true);
          unsigned c2 = (unsigned)__builtin_amdgcn_update_dpp(0, (int)lo, 0x140, 0xf, 0xf, true);
          FPS_COMBINE(a, c2); }
        // lane ^16 : ds_swizzle bitmode xor16 (offset 0x401F)
        { unsigned a = (unsigned)__builtin_amdgcn_ds_swizzle((int)hi, 0x401F);
          unsigned c2 = (unsigned)__builtin_amdgcn_ds_swizzle((int)lo, 0x401F);
          FPS_COMBINE(a, c2); }
        // lane ^32 : cross-half
        { unsigned a = (unsigned)__shfl_xor((int)hi, 32, 64);
          unsigned c2 = (unsigned)__shfl_xor((int)lo, 32, 64);
          FPS_COMBINE(a, c2); }
        #undef FPS_COMBINE

        const int buf = s & 1;
        if ((t & 63) == 0)
            s_slot[buf][t >> 6] = ((unsigned long long)hi << 32) | lo;
        __syncthreads();   // the ONLY barrier per step (slots double-buffered)

        // All threads redundantly reduce the 16 wave results (broadcast reads).
        unsigned long long g = s_slot[buf][0];
        #pragma unroll
        for (int w = 1; w < 16; ++w) {
            unsigned long long v = s_slot[buf][w];
            if (v > g) g = v;
        }
        const int sel = (int)(~(unsigned)g);

        c4 = p4[sel];      // wave-uniform gather of next centroid (1 dwordx4)

        if (t == 0) {
            out_idx[b * S + s] = (float)sel;
            idx_int[b * S + s] = sel;
        }
    }
}

// ---------------------------------------------------------------------------
// Ball query counts: one block (256 thr) per (batch, centroid).
// ---------------------------------------------------------------------------
__launch_bounds__(256)
__global__ void ballq_kernel(const float* __restrict__ ws,
                             const int* __restrict__ idx_int,
                             float* __restrict__ out_counts) {
    __shared__ int s_part[4];
    const int b = blockIdx.x >> 10;
    const int j = blockIdx.x & 1023;
    const int t = threadIdx.x;
    const float* __restrict__ px = ws + (size_t)b * N;
    const float* __restrict__ py = ws + (size_t)(B + b) * N;
    const float* __restrict__ pz = ws + (size_t)(2 * B + b) * N;

    const int ci = idx_int[b * S + j];
    const float cx = px[ci], cy = py[ci], cz = pz[ci];

    int cnt = 0;
    #pragma unroll 4
    for (int p = t; p < N; p += 256) {
        float dx = __fsub_rn(cx, px[p]);
        float dy = __fsub_rn(cy, py[p]);
        float dz = __fsub_rn(cz, pz[p]);
        float d2 = __fadd_rn(__fadd_rn(__fmul_rn(dx, dx), __fmul_rn(dy, dy)),
                             __fmul_rn(dz, dz));
        cnt += (d2 <= RAD2) ? 1 : 0;
    }
    #pragma unroll
    for (int off = 1; off < 64; off <<= 1)
        cnt += __shfl_xor(cnt, off, 64);
    if ((t & 63) == 0) s_part[t >> 6] = cnt;
    __syncthreads();
    if (t == 0)
        out_counts[b * S + j] = (float)(s_part[0] + s_part[1] + s_part[2] + s_part[3]);
}

// ---------------------------------------------------------------------------
extern "C" void kernel_launch(void* const* d_in, const int* in_sizes, int n_in,
                              void* d_out, int out_size, void* d_ws, size_t ws_size,
                              hipStream_t stream) {
    const float* x = (const float*)d_in[0];
    float* out = (float*)d_out;
    float* ws = (float*)d_ws;                       // px|py|pz SoA, float4 pack, idx ints
    int* idx_int = (int*)(ws + (size_t)7 * B * N);  // after SoA (3BN) + float4 (4BN)

    float* out_x      = out;                         // B*N*D floats
    float* out_idx    = out + (size_t)B * N * D;     // B*S floats (idx as f32)
    float* out_counts = out_idx + (size_t)B * S;     // B*S floats (counts as f32)

    hipLaunchKernelGGL(pack_kernel, dim3((B * N + 255) / 256), dim3(256), 0, stream, x, ws);
    hipLaunchKernelGGL(copy_x_kernel, dim3(2048), dim3(256), 0, stream, x, out_x);
    hipLaunchKernelGGL(fps_kernel, dim3(B), dim3(1024), 0, stream, ws, out_idx, idx_int);
    hipLaunchKernelGGL(ballq_kernel, dim3(B * S), dim3(256), 0, stream, ws, idx_int, out_counts);
}

// Round 5
// 2000.771 us; speedup vs baseline: 2.4968x; 2.2544x over previous
//
#include <hip/hip_runtime.h>
#include <math.h>

#define B 4
#define N 32768
#define D 131
#define S 1024
#define RAD2 0.1f      // reference compares d2 <= RADIUS (=0.1) on SQUARED distance
#define G 16           // FPS blocks per batch
#define TPB 256        // FPS threads per block
#define PPT (N / G / TPB)   // 8 points per thread -> ~52 live VGPRs, no spills

// ---------------------------------------------------------------------------
// Copy x (4x32768x131 f32 = 64MB) straight to out. float4 grid-stride.
// ---------------------------------------------------------------------------
__global__ void copy_x_kernel(const float* __restrict__ x, float* __restrict__ out) {
    const size_t total4 = (size_t)B * N * D / 4;
    const float4* __restrict__ src = (const float4*)x;
    float4* __restrict__ dst = (float4*)out;
    for (size_t i = (size_t)blockIdx.x * blockDim.x + threadIdx.x; i < total4;
         i += (size_t)gridDim.x * blockDim.x)
        dst[i] = src[i];
}

// ---------------------------------------------------------------------------
// Pack pts = x[:,:,:3] into SoA (px|py|pz) AND packed float4 {x,y,z,0} for the
// per-step centroid gather (one dwordx4 round-trip).
// ---------------------------------------------------------------------------
__global__ void pack_kernel(const float* __restrict__ x, float* __restrict__ ws) {
    int i = blockIdx.x * blockDim.x + threadIdx.x;
    if (i < B * N) {
        const float* __restrict__ s = x + (size_t)i * D;
        float a = s[0], bb = s[1], c = s[2];
        ws[i]             = a;
        ws[B * N + i]     = bb;
        ws[2 * B * N + i] = c;
        float4* w4 = (float4*)(ws + (size_t)3 * B * N);
        w4[i] = make_float4(a, bb, c, 0.0f);
    }
}

// ---------------------------------------------------------------------------
// Multi-block FPS: G=16 blocks per batch, 256 thr/block, 8 pts/thread.
// ALL state (x,y,z,closest) in registers -> no spills at the 64-VGPR budget.
// Per-step cross-block exchange via 16 u64 slots in ws (agent-scope atomics,
// relaxed: the 8B key is the entire payload, tag embedded in low bits).
// key = [f32 bits of best : 32][ (32767-idx) : 15 ][ 0 : 6 ][ tag=s+1 : 11 ]
//   - tags equal within a step  => u64 max == (max value, then min index)
//   - tag check distinguishes this step's value from stale (double-buffered,
//     happens-before via the poll makes overwrite safe)
// ---------------------------------------------------------------------------
__launch_bounds__(TPB)
__global__ void fps_kernel(const float* __restrict__ ws,
                           unsigned long long* __restrict__ gslot,  // [B][2][G], zeroed
                           float* __restrict__ out_idx,
                           int* __restrict__ idx_int) {
    const int b = blockIdx.x / G;
    const int g = blockIdx.x % G;
    const int t = threadIdx.x;
    const int w = t >> 6;       // wave 0..3
    const int lane = t & 63;

    __shared__ unsigned long long s_slot[2][4];
    __shared__ int s_selbuf[2];

    const float* __restrict__ px = ws + (size_t)b * N;
    const float* __restrict__ py = ws + (size_t)(B + b) * N;
    const float* __restrict__ pz = ws + (size_t)(2 * B + b) * N;
    const float4* __restrict__ p4 = (const float4*)(ws + (size_t)3 * B * N) + (size_t)b * N;
    unsigned long long* __restrict__ slots = gslot + (size_t)b * 2 * G;

    // Thread owns points p = base + 2*t + 512*i + {0,1}, i=0..3 (ascending p).
    const int base = g * (N / G);
    float lx[PPT], ly[PPT], lz[PPT], lcl[PPT];
    #pragma unroll
    for (int i = 0; i < PPT / 2; ++i) {
        int p = base + 2 * t + 2 * TPB * i;
        float2 vx = *(const float2*)&px[p];
        float2 vy = *(const float2*)&py[p];
        float2 vz = *(const float2*)&pz[p];
        lx[2*i] = vx.x; lx[2*i+1] = vx.y;
        ly[2*i] = vy.x; ly[2*i+1] = vy.y;
        lz[2*i] = vz.x; lz[2*i+1] = vz.y;
        lcl[2*i] = INFINITY; lcl[2*i+1] = INFINITY;
    }

    float4 c4 = p4[0];   // centroid 0 (reference starts at sel=0)

    for (int s = 0; s < S; ++s) {
        const float cx = c4.x, cy = c4.y, cz = c4.z;

        float best = -INFINITY;
        int   bidx = 0;
        #pragma unroll
        for (int i = 0; i < PPT / 2; ++i) {
            const int p = base + 2 * t + 2 * TPB * i;
            {
                float dx = __fsub_rn(cx, lx[2*i]);
                float dy = __fsub_rn(cy, ly[2*i]);
                float dz = __fsub_rn(cz, lz[2*i]);
                float d2 = __fadd_rn(__fadd_rn(__fmul_rn(dx, dx), __fmul_rn(dy, dy)),
                                     __fmul_rn(dz, dz));
                float c = fminf(lcl[2*i], d2);
                lcl[2*i] = c;
                if (c > best) { best = c; bidx = p; }     // strict >: smallest p wins
            }
            {
                float dx = __fsub_rn(cx, lx[2*i+1]);
                float dy = __fsub_rn(cy, ly[2*i+1]);
                float dz = __fsub_rn(cz, lz[2*i+1]);
                float d2 = __fadd_rn(__fadd_rn(__fmul_rn(dx, dx), __fmul_rn(dy, dy)),
                                     __fmul_rn(dz, dz));
                float c = fminf(lcl[2*i+1], d2);
                lcl[2*i+1] = c;
                if (c > best) { best = c; bidx = p + 1; }
            }
        }

        // intra-wave butterfly argmax on (value, smallest idx)
        unsigned hi = __float_as_uint(best);          // best >= 0 => bits monotone
        unsigned lo2 = (unsigned)(32767 - bidx);      // bigger == smaller idx

        #define FPS_COMBINE(OHI, OLO) \
            { unsigned _oh = (OHI), _ol = (OLO); \
              if (_oh > hi || (_oh == hi && _ol > lo2)) { hi = _oh; lo2 = _ol; } }
        { unsigned a = (unsigned)__builtin_amdgcn_update_dpp(0, (int)hi, 0xB1, 0xf, 0xf, true);
          unsigned c2 = (unsigned)__builtin_amdgcn_update_dpp(0, (int)lo2, 0xB1, 0xf, 0xf, true);
          FPS_COMBINE(a, c2); }
        { unsigned a = (unsigned)__builtin_amdgcn_update_dpp(0, (int)hi, 0x4E, 0xf, 0xf, true);
          unsigned c2 = (unsigned)__builtin_amdgcn_update_dpp(0, (int)lo2, 0x4E, 0xf, 0xf, true);
          FPS_COMBINE(a, c2); }
        { unsigned a = (unsigned)__builtin_amdgcn_update_dpp(0, (int)hi, 0x141, 0xf, 0xf, true);
          unsigned c2 = (unsigned)__builtin_amdgcn_update_dpp(0, (int)lo2, 0x141, 0xf, 0xf, true);
          FPS_COMBINE(a, c2); }
        { unsigned a = (unsigned)__builtin_amdgcn_update_dpp(0, (int)hi, 0x140, 0xf, 0xf, true);
          unsigned c2 = (unsigned)__builtin_amdgcn_update_dpp(0, (int)lo2, 0x140, 0xf, 0xf, true);
          FPS_COMBINE(a, c2); }
        { unsigned a = (unsigned)__builtin_amdgcn_ds_swizzle((int)hi, 0x401F);
          unsigned c2 = (unsigned)__builtin_amdgcn_ds_swizzle((int)lo2, 0x401F);
          FPS_COMBINE(a, c2); }
        { unsigned a = (unsigned)__shfl_xor((int)hi, 32, 64);
          unsigned c2 = (unsigned)__shfl_xor((int)lo2, 32, 64);
          FPS_COMBINE(a, c2); }
        #undef FPS_COMBINE

        const int buf = s & 1;
        const unsigned tag = (unsigned)(s + 1);      // 1..1024, 11 bits, never 0
        if (lane == 0)
            s_slot[buf][w] = ((unsigned long long)hi << 32) | ((unsigned long long)lo2 << 17) | tag;
        __syncthreads();

        if (w == 0) {
            // block-level reduce of 4 wave keys (tags equal -> plain u64 max)
            unsigned long long k = s_slot[buf][0];
            #pragma unroll
            for (int j = 1; j < 4; ++j) { unsigned long long v = s_slot[buf][j]; if (v > k) k = v; }
            if (lane == 0)
                __hip_atomic_store(&slots[buf * G + g], k, __ATOMIC_RELAXED,
                                   __HIP_MEMORY_SCOPE_AGENT);
            // poll all 16 slots (lanes duplicate x4 -> one coalesced 128B load/round)
            unsigned long long kk;
            unsigned long long* myslot = &slots[buf * G + (lane & 15)];
            do {
                kk = __hip_atomic_load(myslot, __ATOMIC_RELAXED, __HIP_MEMORY_SCOPE_AGENT);
            } while (__any((unsigned)(kk & 0x7FFull) != tag));
            // max over the 16 distinct slots
            #pragma unroll
            for (int off = 1; off < 16; off <<= 1) {
                unsigned long long o = (unsigned long long)__shfl_xor((long long)kk, off, 64);
                if (o > kk) kk = o;
            }
            if (lane == 0) {
                int sel = 32767 - (int)((kk >> 17) & 0x7FFF);
                s_selbuf[buf] = sel;
                if (g == 0) {
                    out_idx[b * S + s] = (float)sel;
                    idx_int[b * S + s] = sel;
                }
            }
        }
        __syncthreads();
        c4 = p4[s_selbuf[buf]];   // uniform gather of next centroid
    }
}

// ---------------------------------------------------------------------------
// Ball query counts: one block (256 thr) per (batch, centroid).
// ---------------------------------------------------------------------------
__launch_bounds__(256)
__global__ void ballq_kernel(const float* __restrict__ ws,
                             const int* __restrict__ idx_int,
                             float* __restrict__ out_counts) {
    __shared__ int s_part[4];
    const int b = blockIdx.x >> 10;
    const int j = blockIdx.x & 1023;
    const int t = threadIdx.x;
    const float* __restrict__ px = ws + (size_t)b * N;
    const float* __restrict__ py = ws + (size_t)(B + b) * N;
    const float* __restrict__ pz = ws + (size_t)(2 * B + b) * N;

    const int ci = idx_int[b * S + j];
    const float cx = px[ci], cy = py[ci], cz = pz[ci];

    int cnt = 0;
    #pragma unroll 4
    for (int p = t; p < N; p += 256) {
        float dx = __fsub_rn(cx, px[p]);
        float dy = __fsub_rn(cy, py[p]);
        float dz = __fsub_rn(cz, pz[p]);
        float d2 = __fadd_rn(__fadd_rn(__fmul_rn(dx, dx), __fmul_rn(dy, dy)),
                             __fmul_rn(dz, dz));
        cnt += (d2 <= RAD2) ? 1 : 0;
    }
    #pragma unroll
    for (int off = 1; off < 64; off <<= 1)
        cnt += __shfl_xor(cnt, off, 64);
    if ((t & 63) == 0) s_part[t >> 6] = cnt;
    __syncthreads();
    if (t == 0)
        out_counts[b * S + j] = (float)(s_part[0] + s_part[1] + s_part[2] + s_part[3]);
}

// ---------------------------------------------------------------------------
extern "C" void kernel_launch(void* const* d_in, const int* in_sizes, int n_in,
                              void* d_out, int out_size, void* d_ws, size_t ws_size,
                              hipStream_t stream) {
    const float* x = (const float*)d_in[0];
    float* out = (float*)d_out;
    float* ws = (float*)d_ws;   // layout: px|py|pz (3BN) | float4 pack (4BN) | idx ints | slots
    int* idx_int = (int*)(ws + (size_t)7 * B * N);
    unsigned long long* gslot = (unsigned long long*)(idx_int + B * S);  // 8B-aligned

    float* out_x      = out;                         // B*N*D floats
    float* out_idx    = out + (size_t)B * N * D;     // B*S floats (idx as f32)
    float* out_counts = out_idx + (size_t)B * S;     // B*S floats (counts as f32)

    // zero the B*2*G u64 sync slots every launch (deterministic, capturable)
    hipMemsetAsync(gslot, 0, (size_t)B * 2 * G * sizeof(unsigned long long), stream);

    hipLaunchKernelGGL(pack_kernel, dim3((B * N + 255) / 256), dim3(256), 0, stream, x, ws);
    hipLaunchKernelGGL(copy_x_kernel, dim3(2048), dim3(256), 0, stream, x, out_x);
    hipLaunchKernelGGL(fps_kernel, dim3(B * G), dim3(TPB), 0, stream, ws, gslot, out_idx, idx_int);
    hipLaunchKernelGGL(ballq_kernel, dim3(B * S), dim3(256), 0, stream, ws, idx_int, out_counts);
}